// Round 6
// baseline (19.074 us; speedup 1.0000x reference)
//
#include <hip/hip_runtime.h>

namespace {

constexpr int Dd = 6;
constexpr int Nn = 256;
constexpr int Rr = 16;

typedef __attribute__((ext_vector_type(8))) short bf16x8;
typedef __attribute__((ext_vector_type(4))) float f32x4;
typedef __attribute__((ext_vector_type(4))) int i32x4;

// Pade(5,4) tanh: x(945+105u+u^2)/(945+420u+15u^2), u=x^2, output-clamped to [-1,1].
// Interior |err| <= 1.2e-3 (worst near |x|~3.5, rare tail), <2e-5 for |x|<2 —
// below bf16 RNE everywhere it matters. Rational crosses 1 at x~3.8 and stays
// >=1 monotonically after (checked x=5,8,15,30), so v_med3 clamp covers all
// large |x|. No overflow/NaN for |x| < 4e9 (projection values bounded ~15).
// 8 VALU + 1 trans (vs exp2 version's 3 VALU + 2 trans): halves trans-pipe load.
__device__ __forceinline__ float fast_tanh(float xv) {
  const float u = xv * xv;
  float p = u + 105.0f;
  p = fmaf(p, u, 945.0f);                 // u^2 + 105u + 945
  const float num = p * xv;
  float den = fmaf(15.0f, u, 420.0f);
  den = fmaf(den, u, 945.0f);             // 15u^2 + 420u + 945
  const float t = num * __builtin_amdgcn_rcpf(den);
  return __builtin_amdgcn_fmed3f(t, -1.0f, 1.0f);
}

// f32 pair -> packed bf16 (RNE); dst.lo = bf16(a), dst.hi = bf16(b)  [R2-R4 proven]
__device__ __forceinline__ unsigned pack_bf16(float a, float b) {
  unsigned r;
  asm("v_cvt_pk_bf16_f32 %0, %1, %2" : "=v"(r) : "v"(a), "v"(b));
  return r;
}

// block = 128 threads = 2 waves; one block per batch; wave h owns n in [h*128, h*128+128)
__global__ __launch_bounds__(128, 4) void att_h_fused(
    const float* __restrict__ x,   // [B, D, N]
    const float* __restrict__ L,   // [B, N, N] (row 0 only)
    const float* __restrict__ Aq,  // [R, D]
    const float* __restrict__ Ak,  // [R, D]
    const float* __restrict__ Av,  // [R, D]
    const float* __restrict__ Ao,  // [1, R]
    float* __restrict__ out)       // [B, 1]
{
  __shared__ __align__(16) float xs[2][Dd][128];   // per-wave x half
  __shared__ __align__(16) f32x4 accbuf[2][64];    // score partial exchange
  __shared__ float hs[2];

  const int b    = blockIdx.x;
  const int tid  = threadIdx.x;
  const int h    = tid >> 6;
  const int lane = tid & 63;

  const float* xb = x + (size_t)b * (Dd * Nn);

  // ---- stage this wave's x half into LDS (coalesced 16B/lane)
#pragma unroll
  for (int i = 0; i < 3; ++i) {
    const int d = 2 * i + (lane >> 5);
    const int c = (lane & 31) * 4;
    *(float4*)&xs[h][d][c] = *(const float4*)(xb + d * Nn + h * 128 + c);
  }

  // ---- numNeighbors from L row 0
  const float4 lr = *(const float4*)(L + (size_t)b * Nn * Nn + lane * 4);
  float cnt = (float)(lr.x >= 1.0f) + (float)(lr.y >= 1.0f) +
              (float)(lr.z >= 1.0f) + (float)(lr.w >= 1.0f);
#pragma unroll
  for (int o = 1; o < 64; o <<= 1) cnt += __shfl_xor(cnt, o);
  const float scale = rsqrtf(cnt + 1.0f);

  // ---- this lane's A rows (r = lane&15)
  const int r     = lane & 15;
  const int quart = lane >> 4;
  float aqr[Dd], akr[Dd];
#pragma unroll
  for (int p = 0; p < 3; ++p) {
    const float2 a = *(const float2*)(Aq + r * Dd + 2 * p);
    const float2 c = *(const float2*)(Ak + r * Dd + 2 * p);
    aqr[2 * p] = a.x; aqr[2 * p + 1] = a.y;
    akr[2 * p] = c.x; akr[2 * p + 1] = c.y;
  }

  // ---- main loop over this half's 4 k-blocks: fragments from LDS broadcast reads
  f32x4 acc0 = {0.f, 0.f, 0.f, 0.f}, acc1 = {0.f, 0.f, 0.f, 0.f};
#pragma unroll 2
  for (int kb = 0; kb < 4; ++kb) {
    const int nw = kb * 32 + quart * 8;
    float xa[Dd][8];
#pragma unroll
    for (int d = 0; d < Dd; ++d) {
      const float4 t0 = *(const float4*)&xs[h][d][nw];
      const float4 t1 = *(const float4*)&xs[h][d][nw + 4];
      xa[d][0] = t0.x; xa[d][1] = t0.y; xa[d][2] = t0.z; xa[d][3] = t0.w;
      xa[d][4] = t1.x; xa[d][5] = t1.y; xa[d][6] = t1.z; xa[d][7] = t1.w;
    }
    float qv[8], kv[8];
#pragma unroll
    for (int j = 0; j < 8; ++j) {
      float aq = 0.0f, ak = 0.0f;
#pragma unroll
      for (int d = 0; d < Dd; ++d) {
        aq = fmaf(aqr[d], xa[d][j], aq);
        ak = fmaf(akr[d], xa[d][j], ak);
      }
      qv[j] = fast_tanh(aq);
      kv[j] = fast_tanh(ak);
    }
    i32x4 qp, kp;
#pragma unroll
    for (int p = 0; p < 4; ++p) {
      qp[p] = (int)pack_bf16(qv[2 * p], qv[2 * p + 1]);
      kp[p] = (int)pack_bf16(kv[2 * p], kv[2 * p + 1]);
    }
    const bf16x8 qa = __builtin_bit_cast(bf16x8, qp);
    const bf16x8 ka = __builtin_bit_cast(bf16x8, kp);
    if (kb & 1)
      acc1 = __builtin_amdgcn_mfma_f32_16x16x32_bf16(qa, ka, acc1, 0, 0, 0);
    else
      acc0 = __builtin_amdgcn_mfma_f32_16x16x32_bf16(qa, ka, acc0, 0, 0, 0);
  }

  // ---- exchange score partials between the two waves
  accbuf[h][lane] = acc0 + acc1;
  __syncthreads();
  const f32x4 acc = acc0 + acc1 + accbuf[1 - h][lane];

  // ---- softmax over s + w[s] = Ao . attn[:,s]  (C/D: s=lane&15, r=quart*4+j)
  const float4 ao4 = *(const float4*)(Ao + quart * 4);
  const float aoarr[4] = {ao4.x, ao4.y, ao4.z, ao4.w};
  float wp = 0.0f;
#pragma unroll
  for (int j = 0; j < 4; ++j) {
    const float sc = acc[j] * scale;
    float mj = sc;
#pragma unroll
    for (int o = 1; o < 16; o <<= 1) mj = fmaxf(mj, __shfl_xor(mj, o));
    const float ej = __builtin_amdgcn_exp2f((sc - mj) * 1.4426950408889634f);
    float sj = ej;
#pragma unroll
    for (int o = 1; o < 16; o <<= 1) sj += __shfl_xor(sj, o);
    wp = fmaf(aoarr[j], ej * __builtin_amdgcn_rcpf(sj), wp);
  }
  wp += __shfl_xor(wp, 16);
  wp += __shfl_xor(wp, 32);
  float wb[Rr];
#pragma unroll
  for (int s = 0; s < Rr; ++s) wb[s] = __shfl(wp, s);

  // ---- epilogue: this wave's 128 columns, 2 per lane, x from LDS
  float hsum = 0.0f;
#pragma unroll
  for (int c = 0; c < 2; ++c) {
    float xcv[Dd];
#pragma unroll
    for (int d = 0; d < Dd; ++d) xcv[d] = xs[h][d][lane * 2 + c];
    float hv = 0.0f;
#pragma unroll
    for (int s = 0; s < Rr; ++s) {
      float av = 0.0f;
#pragma unroll
      for (int d = 0; d < Dd; ++d) av = fmaf(Av[s * Dd + d], xcv[d], av);
      hv = fmaf(wb[s], fast_tanh(av), hv);
    }
    hsum += hv * __builtin_amdgcn_rcpf(
                     1.0f + __builtin_amdgcn_exp2f(-1.4426950408889634f * hv));
  }
#pragma unroll
  for (int o = 1; o < 64; o <<= 1) hsum += __shfl_xor(hsum, o);
  if (lane == 0) hs[h] = hsum;
  __syncthreads();
  if (tid == 0) {
    const float tot = hs[0] + hs[1];
    out[b] = tot * tot;
  }
}

}  // namespace

extern "C" void kernel_launch(void* const* d_in, const int* in_sizes, int n_in,
                              void* d_out, int out_size, void* d_ws, size_t ws_size,
                              hipStream_t stream) {
  const float* x  = (const float*)d_in[0];
  const float* L  = (const float*)d_in[1];
  const float* Aq = (const float*)d_in[2];
  const float* Ak = (const float*)d_in[3];
  const float* Av = (const float*)d_in[4];
  const float* Ao = (const float*)d_in[5];
  float* out = (float*)d_out;

  const int B = in_sizes[0] / (Dd * Nn);  // 2048
  att_h_fused<<<dim3(B), dim3(128), 0, stream>>>(x, L, Aq, Ak, Av, Ao, out);
}

// Round 7
// 16.898 us; speedup vs baseline: 1.1288x; 1.1288x over previous
//
#include <hip/hip_runtime.h>

namespace {

constexpr int Dd = 6;
constexpr int Nn = 256;
constexpr int Rr = 16;

typedef __attribute__((ext_vector_type(8))) short bf16x8;
typedef __attribute__((ext_vector_type(4))) float f32x4;
typedef __attribute__((ext_vector_type(4))) int i32x4;

// tanh(x) = 1 - 2/(exp2(2x*log2e)+1); exact saturation via rcp(inf)=0. 3 VALU + 2 trans.
// Proven fastest R2-R4 (Pade regression R6: +5 VALU and 9-deep chain beat the trans savings).
__device__ __forceinline__ float fast_tanh(float xv) {
  float e = __builtin_amdgcn_exp2f(xv * 2.8853900817779268f);
  return fmaf(-2.0f, __builtin_amdgcn_rcpf(e + 1.0f), 1.0f);
}

// f32 pair -> packed bf16 (RNE); dst.lo=bf16(a), dst.hi=bf16(b)  [R2-R6 proven]
__device__ __forceinline__ unsigned pack_bf16(float a, float b) {
  unsigned r;
  asm("v_cvt_pk_bf16_f32 %0, %1, %2" : "=v"(r) : "v"(a), "v"(b));
  return r;
}

// 256 threads = 4 waves; one block per batch; wave w owns n in [w*64, w*64+64)
__global__ __launch_bounds__(256, 6) void att_h_fused(
    const float* __restrict__ x,   // [B, D, N]
    const float* __restrict__ L,   // [B, N, N] (row 0 only)
    const float* __restrict__ Aq,  // [R, D]
    const float* __restrict__ Ak,  // [R, D]
    const float* __restrict__ Av,  // [R, D]
    const float* __restrict__ Ao,  // [1, R]
    float* __restrict__ out)       // [B, 1]
{
  __shared__ __align__(16) float xs[Dd][Nn];     // x panel; wave-private windows -> no barrier
  __shared__ __align__(16) f32x4 accbuf[4][64];  // score partial exchange
  __shared__ float hs[4];

  const int b    = blockIdx.x;
  const int tid  = threadIdx.x;
  const int w    = tid >> 6;
  const int lane = tid & 63;

  const float* xb = x + (size_t)b * (Dd * Nn);

  // ---- stage this wave's 64-column window (float2/lane x3, coalesced 8B)
  {
    const int c = (lane & 31) * 2 + w * 64;
#pragma unroll
    for (int i = 0; i < 3; ++i) {
      const int d = 2 * i + (lane >> 5);
      *(float2*)&xs[d][c] = *(const float2*)(xb + d * Nn + c);
    }
  }

  // ---- numNeighbors from L row 0 (per-wave duplicate; L1/L2 hit for waves 1-3)
  const float4 lr = *(const float4*)(L + (size_t)b * Nn * Nn + lane * 4);
  float cnt = (float)(lr.x >= 1.0f) + (float)(lr.y >= 1.0f) +
              (float)(lr.z >= 1.0f) + (float)(lr.w >= 1.0f);
#pragma unroll
  for (int o = 1; o < 64; o <<= 1) cnt += __shfl_xor(cnt, o);
  const float scale = rsqrtf(cnt + 1.0f);

  // ---- this lane's A rows (r = lane&15)
  const int r     = lane & 15;
  const int quart = lane >> 4;
  float aqr[Dd], akr[Dd];
#pragma unroll
  for (int p = 0; p < 3; ++p) {
    const float2 a = *(const float2*)(Aq + r * Dd + 2 * p);
    const float2 c = *(const float2*)(Ak + r * Dd + 2 * p);
    aqr[2 * p] = a.x; aqr[2 * p + 1] = a.y;
    akr[2 * p] = c.x; akr[2 * p + 1] = c.y;
  }

  // ---- 2 k-blocks of 32 columns: stream d, accumulate 8 j-lanes (low VGPR)
  f32x4 acc0 = {0.f, 0.f, 0.f, 0.f}, acc1 = {0.f, 0.f, 0.f, 0.f};
#pragma unroll
  for (int kb = 0; kb < 2; ++kb) {
    const int nw = w * 64 + kb * 32 + quart * 8;
    float aq[8] = {0.f, 0.f, 0.f, 0.f, 0.f, 0.f, 0.f, 0.f};
    float ak[8] = {0.f, 0.f, 0.f, 0.f, 0.f, 0.f, 0.f, 0.f};
#pragma unroll
    for (int d = 0; d < Dd; ++d) {
      const float4 t0 = *(const float4*)&xs[d][nw];
      const float4 t1 = *(const float4*)&xs[d][nw + 4];
      const float xv[8] = {t0.x, t0.y, t0.z, t0.w, t1.x, t1.y, t1.z, t1.w};
#pragma unroll
      for (int j = 0; j < 8; ++j) {
        aq[j] = fmaf(aqr[d], xv[j], aq[j]);
        ak[j] = fmaf(akr[d], xv[j], ak[j]);
      }
    }
    i32x4 qp, kp;
#pragma unroll
    for (int p = 0; p < 4; ++p) {
      qp[p] = (int)pack_bf16(fast_tanh(aq[2 * p]), fast_tanh(aq[2 * p + 1]));
      kp[p] = (int)pack_bf16(fast_tanh(ak[2 * p]), fast_tanh(ak[2 * p + 1]));
    }
    const bf16x8 qa = __builtin_bit_cast(bf16x8, qp);
    const bf16x8 ka = __builtin_bit_cast(bf16x8, kp);
    if (kb & 1)
      acc1 = __builtin_amdgcn_mfma_f32_16x16x32_bf16(qa, ka, acc1, 0, 0, 0);
    else
      acc0 = __builtin_amdgcn_mfma_f32_16x16x32_bf16(qa, ka, acc0, 0, 0, 0);
  }

  // ---- exchange score partials across the 4 waves
  accbuf[w][lane] = acc0 + acc1;
  __syncthreads();
  f32x4 acc = accbuf[0][lane] + accbuf[1][lane];
  acc += accbuf[2][lane] + accbuf[3][lane];

  // ---- softmax over s + w[s] = Ao . attn[:,s]  (C/D: s=lane&15, r=quart*4+j; per-wave dup)
  const float4 ao4 = *(const float4*)(Ao + quart * 4);
  const float aoarr[4] = {ao4.x, ao4.y, ao4.z, ao4.w};
  float wp = 0.0f;
#pragma unroll
  for (int j = 0; j < 4; ++j) {
    const float sc = acc[j] * scale;
    float mj = sc;
#pragma unroll
    for (int o = 1; o < 16; o <<= 1) mj = fmaxf(mj, __shfl_xor(mj, o));
    const float ej = __builtin_amdgcn_exp2f((sc - mj) * 1.4426950408889634f);
    float sj = ej;
#pragma unroll
    for (int o = 1; o < 16; o <<= 1) sj += __shfl_xor(sj, o);
    wp = fmaf(aoarr[j], ej * __builtin_amdgcn_rcpf(sj), wp);
  }
  wp += __shfl_xor(wp, 16);
  wp += __shfl_xor(wp, 32);
  float wb[Rr];
#pragma unroll
  for (int s = 0; s < Rr; ++s) wb[s] = __shfl(wp, s);

  // ---- epilogue: 1 column per lane (c = w*64+lane), x from same-wave LDS window
  float xcv[Dd];
#pragma unroll
  for (int d = 0; d < Dd; ++d) xcv[d] = xs[d][w * 64 + lane];
  float hv = 0.0f;
#pragma unroll
  for (int s = 0; s < Rr; ++s) {
    float av = 0.0f;
#pragma unroll
    for (int d = 0; d < Dd; ++d) av = fmaf(Av[s * Dd + d], xcv[d], av);
    hv = fmaf(wb[s], fast_tanh(av), hv);
  }
  float hsum = hv * __builtin_amdgcn_rcpf(
                        1.0f + __builtin_amdgcn_exp2f(-1.4426950408889634f * hv));
#pragma unroll
  for (int o = 1; o < 64; o <<= 1) hsum += __shfl_xor(hsum, o);
  if (lane == 0) hs[w] = hsum;
  __syncthreads();
  if (tid == 0) {
    const float tot = hs[0] + hs[1] + hs[2] + hs[3];
    out[b] = tot * tot;
  }
}

}  // namespace

extern "C" void kernel_launch(void* const* d_in, const int* in_sizes, int n_in,
                              void* d_out, int out_size, void* d_ws, size_t ws_size,
                              hipStream_t stream) {
  const float* x  = (const float*)d_in[0];
  const float* L  = (const float*)d_in[1];
  const float* Aq = (const float*)d_in[2];
  const float* Ak = (const float*)d_in[3];
  const float* Av = (const float*)d_in[4];
  const float* Ao = (const float*)d_in[5];
  float* out = (float*)d_out;

  const int B = in_sizes[0] / (Dd * Nn);  // 2048
  att_h_fused<<<dim3(B), dim3(256), 0, stream>>>(x, L, Aq, Ak, Av, Ao, out);
}